// Round 12
// baseline (247.687 us; speedup 1.0000x reference)
//
#include <hip/hip_runtime.h>
#include <hip/hip_bf16.h>

#define M_TOK 8192
#define IN_F  1024
#define OUT_F 1024
#define N_EXP 8
#define KT    8192   // stacked K: 8 experts x 1024 (B side only)

typedef __attribute__((ext_vector_type(8)))  _Float16 f16x8;
typedef __attribute__((ext_vector_type(4)))  _Float16 f16x4;
typedef __attribute__((ext_vector_type(4)))  float    f32x4;
typedef __attribute__((ext_vector_type(16))) float    f32x16;

// ---------------- merged prep: gate+convert (blocks 0..511) | transpose (512..2559) ----------------
__global__ __launch_bounds__(256) void moe_prep_kernel(
    const float* __restrict__ x, const float* __restrict__ Wg,
    const float* __restrict__ bg, const float* __restrict__ We,
    float* __restrict__ g, _Float16* __restrict__ xh, _Float16* __restrict__ wt)
{
    __shared__ float t[64][65];
    const int bid = blockIdx.x;
    if (bid < 512) {
        // ---- gate softmax + x -> f16, 16 tokens/block (4 per wave) ----
        const int lane = threadIdx.x & 63;
        const int wave = threadIdx.x >> 6;
        const int t0 = bid * 16 + wave * 4;
        const float* xr0 = x + (size_t)t0 * IN_F;

        float acc[4][8] = {};
#pragma unroll
        for (int kc = 0; kc < 4; ++kc) {
            const int i = kc * 256 + lane * 4;
            float4 xv[4];
#pragma unroll
            for (int tk = 0; tk < 4; ++tk) xv[tk] = *(const float4*)(xr0 + (size_t)tk * IN_F + i);
            float xs[4][4];
#pragma unroll
            for (int tk = 0; tk < 4; ++tk) {
                xs[tk][0] = xv[tk].x; xs[tk][1] = xv[tk].y;
                xs[tk][2] = xv[tk].z; xs[tk][3] = xv[tk].w;
            }
#pragma unroll
            for (int j = 0; j < 4; ++j) {
                const float4* wr = (const float4*)(Wg + (size_t)(i + j) * 8);
                float4 w0 = wr[0], w1 = wr[1];
                float wv[8] = {w0.x, w0.y, w0.z, w0.w, w1.x, w1.y, w1.z, w1.w};
#pragma unroll
                for (int tk = 0; tk < 4; ++tk)
#pragma unroll
                    for (int e = 0; e < 8; ++e)
                        acc[tk][e] = fmaf(xs[tk][j], wv[e], acc[tk][e]);
            }
#pragma unroll
            for (int tk = 0; tk < 4; ++tk) {
                f16x4 h = { (_Float16)xs[tk][0], (_Float16)xs[tk][1],
                            (_Float16)xs[tk][2], (_Float16)xs[tk][3] };
                *(f16x4*)(xh + (size_t)(t0 + tk) * IN_F + i) = h;
            }
        }
#pragma unroll
        for (int tk = 0; tk < 4; ++tk) {
            float a[8];
#pragma unroll
            for (int e = 0; e < 8; ++e) {
                float v = acc[tk][e];
#pragma unroll
                for (int off = 32; off > 0; off >>= 1) v += __shfl_xor(v, off, 64);
                a[e] = v + bg[e];
            }
            float mx = a[0];
#pragma unroll
            for (int e = 1; e < 8; ++e) mx = fmaxf(mx, a[e]);
            float sum = 0.f;
#pragma unroll
            for (int e = 0; e < 8; ++e) { a[e] = __expf(a[e] - mx); sum += a[e]; }
            float inv = 1.0f / sum;
            if (lane == 0) {
                float4 p0 = {a[0] * inv, a[1] * inv, a[2] * inv, a[3] * inv};
                float4 p1 = {a[4] * inv, a[5] * inv, a[6] * inv, a[7] * inv};
                float4* gp = (float4*)(g + (size_t)(t0 + tk) * 8);
                gp[0] = p0; gp[1] = p1;
            }
        }
    } else {
        // ---- We [e][i][o] fp32 -> wt [o][e*1024+i] f16, one 64x64 tile ----
        const int tile = bid - 512;
        const int e  = tile >> 8;
        const int o0 = ((tile >> 4) & 15) * 64;
        const int i0 = (tile & 15) * 64;
        const float* src = We + ((size_t)e << 20);
        const int oo = threadIdx.x & 63;
        const int ib = threadIdx.x >> 6;
#pragma unroll
        for (int r = 0; r < 16; ++r) {
            int i = ib + r * 4;
            t[i][oo] = src[(size_t)(i0 + i) * OUT_F + o0 + oo];
        }
        __syncthreads();
        const int i8 = threadIdx.x & 7;      // i-block (8 consecutive i)
        const int ob = threadIdx.x >> 3;     // 0..31
#pragma unroll
        for (int h = 0; h < 2; ++h) {
            const int o = ob + h * 32;
            float v[8];
#pragma unroll
            for (int j = 0; j < 8; ++j) v[j] = t[i8 * 8 + j][o];
            f16x8 hv = { (_Float16)v[0], (_Float16)v[1], (_Float16)v[2], (_Float16)v[3],
                         (_Float16)v[4], (_Float16)v[5], (_Float16)v[6], (_Float16)v[7] };
            *(f16x8*)(wt + (size_t)(o0 + o) * KT + (size_t)e * 1024 + i0 + i8 * 8) = hv;
        }
    }
}

// ---------------- fused GEMM: out = sum_e g[:,e]*(xh@We[e]) + g-weighted bias ----
// ROUND-5 PROVEN PHASE SCHEDULE (drain-immediately lockstep, FETCH 76.7MB) with
// ONE change confined to the compute section: MFMA shape 16x16x32 -> 32x32x16.
// The 32x32 pipe runs ~20% more FLOP/cyc (m119: 2382 vs m06: 2075 TF) and halves
// MFMA issue slots (16 vs 32 per wave-phase), freeing issue BW for ds_reads.
// Staged bytes / barriers / drains byte-identical -> lockstep preserved.
// Fragments: A/B lane holds 8 f16 at [row=lane&31][k=(lane>>5)*8+j] (systematic
// extension of the verified 16x16x32 mapping); C/D col=lane&31,
// row=(reg&3)+8*(reg>>2)+4*(lane>>5) (HW-verified m74/m101). Same 16B LDS reads,
// same XOR swizzle, same 8-lanes-per-chunk conflict structure.
__device__ __forceinline__ void async16(const void* gp, void* lp) {
    __builtin_amdgcn_global_load_lds((const __attribute__((address_space(1))) void*)gp,
                                     (__attribute__((address_space(3))) void*)lp, 16, 0, 0);
}

__global__ __launch_bounds__(256, 2) void moe_gemm_kernel(
    const _Float16* __restrict__ xh,   // [M][1024] f16
    const _Float16* __restrict__ wt,   // [N][KT] f16  (stacked B'^T)
    const float* __restrict__ g,       // [M][E]
    const float* __restrict__ be,      // [E][N]
    float* __restrict__ out)           // [M][N] fp32
{
    __shared__ __align__(16) _Float16 As[128 * 64];
    __shared__ __align__(16) _Float16 Bs[128 * 64];
    __shared__ float gs[8 * 128];      // gate, transposed [e][row]
    __shared__ float bs[8 * 128];      // bias slice [e][col]

    const int tid  = threadIdx.x;
    const int lane = tid & 63;
    const int wave = tid >> 6;
    const size_t n0 = (size_t)blockIdx.x * 128;
    const size_t m0 = (size_t)blockIdx.y * 128;

    {   // gate block -> transposed [e][row]
        float4 v = ((const float4*)(g + m0 * 8))[tid];
        int row = tid >> 1, e0 = (tid & 1) * 4;
        gs[(e0 + 0) * 128 + row] = v.x;
        gs[(e0 + 1) * 128 + row] = v.y;
        gs[(e0 + 2) * 128 + row] = v.z;
        gs[(e0 + 3) * 128 + row] = v.w;
    }
#pragma unroll
    for (int r = 0; r < 4; ++r) {       // bias slice
        int idx = r * 256 + tid;
        int eb = idx >> 7, col = idx & 127;
        bs[idx] = be[(size_t)eb * 1024 + n0 + col];
    }
    __syncthreads();

    // Staging: linear 16B chunk L = tid -> LDS row = L>>3, phys c8 = L&7.
    // XOR swizzle baked into the GLOBAL source: logical k-chunk = phys_c8 ^ (row&7).
    const int rb = tid >> 3;
    const int c8 = (tid & 7) ^ (rb & 7);
    const _Float16* pA = xh + (m0 + rb) * (size_t)IN_F + c8 * 8;
    const _Float16* pB = wt + (n0 + rb) * (size_t)KT + c8 * 8;
    char* lA = (char*)As + tid * 16;
    char* lB = (char*)Bs + tid * 16;

    // 32x32 fragment geometry. Wave tile 64x64 at (wm, wn); sub-tiles tm,tn in {0,1}.
    const int m32 = lane & 31;
    const int hk  = lane >> 5;           // k-half: k = hk*8 + j
    const int wm  = (wave >> 1) * 64;
    const int wn  = (wave & 1) * 64;
    // LDS byte addr for fragment read: row r, k-step ks (0..3):
    //   r*128 + (((ks*2 + hk) ^ (r & 7)) * 16)
    int raA[2][4], raB[2][4];
#pragma unroll
    for (int tm = 0; tm < 2; ++tm) {
        const int r = wm + tm * 32 + m32;
#pragma unroll
        for (int ks = 0; ks < 4; ++ks)
            raA[tm][ks] = r * 128 + (((ks * 2 + hk) ^ (r & 7)) * 16);
    }
#pragma unroll
    for (int tn = 0; tn < 2; ++tn) {
        const int r = wn + tn * 32 + m32;
#pragma unroll
        for (int ks = 0; ks < 4; ++ks)
            raB[tn][ks] = r * 128 + (((ks * 2 + hk) ^ (r & 7)) * 16);
    }

    // acc init = gate-weighted bias. C/D row = (reg&3) + 8*(reg>>2) + 4*hk.
    f32x16 acc[2][2] = {};
#pragma unroll
    for (int e = 0; e < 8; ++e) {
        const float bb0 = bs[e * 128 + wn + 0  + m32];
        const float bb1 = bs[e * 128 + wn + 32 + m32];
#pragma unroll
        for (int tm = 0; tm < 2; ++tm) {
#pragma unroll
            for (int r = 0; r < 16; ++r) {
                const int crow = (r & 3) + ((r >> 2) << 3) + hk * 4;
                const float gv = gs[e * 128 + wm + tm * 32 + crow];
                acc[tm][0][r] = fmaf(gv, bb0, acc[tm][0][r]);
                acc[tm][1][r] = fmaf(gv, bb1, acc[tm][1][r]);
            }
        }
    }

    // per-lane gate scalars (f16): A-fragment row = wm + tm*32 + m32 (one row/lane)
    _Float16 gh[8][2];
#pragma unroll
    for (int e = 0; e < 8; ++e)
#pragma unroll
        for (int tm = 0; tm < 2; ++tm)
            gh[e][tm] = (_Float16)gs[e * 128 + wm + tm * 32 + m32];

    // kt-outer / expert-inner, drain-immediately lockstep phases (byte-identical
    // staging/barrier structure to the proven kernel).
    for (int kt = 0; kt < 16; ++kt) {
        const _Float16* sA = pA + kt * 64;
#pragma unroll
        for (int j = 0; j < 4; ++j) async16(sA + j * 32 * (size_t)IN_F, lA + j * 4096);

        f16x8 afr[2][4];   // raw A fragments [tm][ks] — loaded at e==0, reused across e
#pragma unroll
        for (int e = 0; e < 8; ++e) {
            const _Float16* sB = pB + e * 1024 + kt * 64;
#pragma unroll
            for (int j = 0; j < 4; ++j) async16(sB + j * 32 * (size_t)KT, lB + j * 4096);
            __syncthreads();   // drains A (e==0) + B stagings; lockstep restoring force
            if (e == 0) {
#pragma unroll
                for (int tm = 0; tm < 2; ++tm)
#pragma unroll
                    for (int ks = 0; ks < 4; ++ks)
                        afr[tm][ks] = *(const f16x8*)((const char*)As + raA[tm][ks]);
            }
            f16x8 bf[2][4];
#pragma unroll
            for (int tn = 0; tn < 2; ++tn)
#pragma unroll
                for (int ks = 0; ks < 4; ++ks)
                    bf[tn][ks] = *(const f16x8*)((const char*)Bs + raB[tn][ks]);
            // gate-scale A fragments (per-lane scalar splat), then 16 MFMA 32x32x16
#pragma unroll
            for (int tm = 0; tm < 2; ++tm) {
                f16x8 af[4];
#pragma unroll
                for (int ks = 0; ks < 4; ++ks) af[ks] = afr[tm][ks] * gh[e][tm];
#pragma unroll
                for (int tn = 0; tn < 2; ++tn)
#pragma unroll
                    for (int ks = 0; ks < 4; ++ks)
                        acc[tm][tn] = __builtin_amdgcn_mfma_f32_32x32x16_f16(
                            af[ks], bf[tn][ks], acc[tm][tn], 0, 0, 0);
            }
            __syncthreads();   // all waves done with Bs (and As on last e) before restage
        }
    }

    // Epilogue: C/D col = lane&31, row = (reg&3) + 8*(reg>>2) + 4*hk.
#pragma unroll
    for (int tm = 0; tm < 2; ++tm) {
#pragma unroll
        for (int tn = 0; tn < 2; ++tn) {
            const size_t col = n0 + wn + tn * 32 + m32;
#pragma unroll
            for (int r = 0; r < 16; ++r) {
                const int crow = (r & 3) + ((r >> 2) << 3) + hk * 4;
                out[(m0 + wm + tm * 32 + crow) * (size_t)OUT_F + col] = acc[tm][tn][r];
            }
        }
    }
}

extern "C" void kernel_launch(void* const* d_in, const int* in_sizes, int n_in,
                              void* d_out, int out_size, void* d_ws, size_t ws_size,
                              hipStream_t stream) {
    const float* x  = (const float*)d_in[0];
    const float* We = (const float*)d_in[1];
    const float* be = (const float*)d_in[2];
    const float* Wg = (const float*)d_in[3];
    const float* bg = (const float*)d_in[4];
    float* out = (float*)d_out;

    char* ws = (char*)d_ws;
    float*    g   = (float*)ws;                                  // 256 KB
    _Float16* xh  = (_Float16*)(ws + (1 << 18));                 // 16 MiB
    _Float16* wt2 = (_Float16*)(ws + (1 << 18) + (1 << 24));     // 16 MiB

    moe_prep_kernel<<<2560, 256, 0, stream>>>(x, Wg, bg, We, g, xh, wt2);
    moe_gemm_kernel<<<dim3(OUT_F / 128, M_TOK / 128), 256, 0, stream>>>(xh, wt2, g, be, out);
}

// Round 13
// 244.976 us; speedup vs baseline: 1.0111x; 1.0111x over previous
//
#include <hip/hip_runtime.h>
#include <hip/hip_bf16.h>

#define M_TOK 8192
#define IN_F  1024
#define OUT_F 1024
#define N_EXP 8
#define KT    8192   // stacked K: 8 experts x 1024 (B side only)

typedef __attribute__((ext_vector_type(8)))  _Float16 f16x8;
typedef __attribute__((ext_vector_type(4)))  _Float16 f16x4;
typedef __attribute__((ext_vector_type(4)))  float    f32x4;
typedef __attribute__((ext_vector_type(16))) float    f32x16;

// ---------------- merged prep: gate+convert (blocks 0..511) | transpose (512..2559) ----------------
__global__ __launch_bounds__(256) void moe_prep_kernel(
    const float* __restrict__ x, const float* __restrict__ Wg,
    const float* __restrict__ bg, const float* __restrict__ We,
    float* __restrict__ g, _Float16* __restrict__ xh, _Float16* __restrict__ wt)
{
    __shared__ float t[64][65];
    const int bid = blockIdx.x;
    if (bid < 512) {
        // ---- gate softmax + x -> f16, 16 tokens/block (4 per wave) ----
        const int lane = threadIdx.x & 63;
        const int wave = threadIdx.x >> 6;
        const int t0 = bid * 16 + wave * 4;
        const float* xr0 = x + (size_t)t0 * IN_F;

        float acc[4][8] = {};
#pragma unroll
        for (int kc = 0; kc < 4; ++kc) {
            const int i = kc * 256 + lane * 4;
            float4 xv[4];
#pragma unroll
            for (int tk = 0; tk < 4; ++tk) xv[tk] = *(const float4*)(xr0 + (size_t)tk * IN_F + i);
            float xs[4][4];
#pragma unroll
            for (int tk = 0; tk < 4; ++tk) {
                xs[tk][0] = xv[tk].x; xs[tk][1] = xv[tk].y;
                xs[tk][2] = xv[tk].z; xs[tk][3] = xv[tk].w;
            }
#pragma unroll
            for (int j = 0; j < 4; ++j) {
                const float4* wr = (const float4*)(Wg + (size_t)(i + j) * 8);
                float4 w0 = wr[0], w1 = wr[1];
                float wv[8] = {w0.x, w0.y, w0.z, w0.w, w1.x, w1.y, w1.z, w1.w};
#pragma unroll
                for (int tk = 0; tk < 4; ++tk)
#pragma unroll
                    for (int e = 0; e < 8; ++e)
                        acc[tk][e] = fmaf(xs[tk][j], wv[e], acc[tk][e]);
            }
#pragma unroll
            for (int tk = 0; tk < 4; ++tk) {
                f16x4 h = { (_Float16)xs[tk][0], (_Float16)xs[tk][1],
                            (_Float16)xs[tk][2], (_Float16)xs[tk][3] };
                *(f16x4*)(xh + (size_t)(t0 + tk) * IN_F + i) = h;
            }
        }
#pragma unroll
        for (int tk = 0; tk < 4; ++tk) {
            float a[8];
#pragma unroll
            for (int e = 0; e < 8; ++e) {
                float v = acc[tk][e];
#pragma unroll
                for (int off = 32; off > 0; off >>= 1) v += __shfl_xor(v, off, 64);
                a[e] = v + bg[e];
            }
            float mx = a[0];
#pragma unroll
            for (int e = 1; e < 8; ++e) mx = fmaxf(mx, a[e]);
            float sum = 0.f;
#pragma unroll
            for (int e = 0; e < 8; ++e) { a[e] = __expf(a[e] - mx); sum += a[e]; }
            float inv = 1.0f / sum;
            if (lane == 0) {
                float4 p0 = {a[0] * inv, a[1] * inv, a[2] * inv, a[3] * inv};
                float4 p1 = {a[4] * inv, a[5] * inv, a[6] * inv, a[7] * inv};
                float4* gp = (float4*)(g + (size_t)(t0 + tk) * 8);
                gp[0] = p0; gp[1] = p1;
            }
        }
    } else {
        // ---- We [e][i][o] fp32 -> wt [o][e*1024+i] f16, one 64x64 tile ----
        const int tile = bid - 512;
        const int e  = tile >> 8;
        const int o0 = ((tile >> 4) & 15) * 64;
        const int i0 = (tile & 15) * 64;
        const float* src = We + ((size_t)e << 20);
        const int oo = threadIdx.x & 63;
        const int ib = threadIdx.x >> 6;
#pragma unroll
        for (int r = 0; r < 16; ++r) {
            int i = ib + r * 4;
            t[i][oo] = src[(size_t)(i0 + i) * OUT_F + o0 + oo];
        }
        __syncthreads();
        const int i8 = threadIdx.x & 7;      // i-block (8 consecutive i)
        const int ob = threadIdx.x >> 3;     // 0..31
#pragma unroll
        for (int h = 0; h < 2; ++h) {
            const int o = ob + h * 32;
            float v[8];
#pragma unroll
            for (int j = 0; j < 8; ++j) v[j] = t[i8 * 8 + j][o];
            f16x8 hv = { (_Float16)v[0], (_Float16)v[1], (_Float16)v[2], (_Float16)v[3],
                         (_Float16)v[4], (_Float16)v[5], (_Float16)v[6], (_Float16)v[7] };
            *(f16x8*)(wt + (size_t)(o0 + o) * KT + (size_t)e * 1024 + i0 + i8 * 8) = hv;
        }
    }
}

// ---------------- fused GEMM: out = sum_e g[:,e]*(xh@We[e]) + g-weighted bias ----
// ROUND-5 PROVEN PHASE SCHEDULE + 32x32x16 MFMA (round 12), with the read/stage
// swizzle FIXED for the 32x32 fragment geometry. Round-12 diagnosis: f(r)=r&7
// left stride-8 co-scheduled lanes (same r&7, hk toggling only bit0 of k-chunk)
// on the same 16B slot -> 4-way bank conflict, SQ_LDS_BANK_CONFLICT 16K->9.45M.
// Fix: f(r) = (r&7) ^ ((r>>3)&7). Stride-8 lanes now differ in r>>3 -> distinct
// slots; consecutive-8 lanes distinct via r&7; hk halves overlap at worst 2-way
// (free, m136). Staging source chunk (rule #21, both-sides-or-neither):
// c8 = (tid&7) ^ (rb&7) ^ (rb>>3) ^ 4*(j&1)  -- odd staging rounds j XOR by 4,
// handled by an even/odd pointer pair. Schedule/barriers/bytes unchanged.
__device__ __forceinline__ void async16(const void* gp, void* lp) {
    __builtin_amdgcn_global_load_lds((const __attribute__((address_space(1))) void*)gp,
                                     (__attribute__((address_space(3))) void*)lp, 16, 0, 0);
}

__global__ __launch_bounds__(256, 2) void moe_gemm_kernel(
    const _Float16* __restrict__ xh,   // [M][1024] f16
    const _Float16* __restrict__ wt,   // [N][KT] f16  (stacked B'^T)
    const float* __restrict__ g,       // [M][E]
    const float* __restrict__ be,      // [E][N]
    float* __restrict__ out)           // [M][N] fp32
{
    __shared__ __align__(16) _Float16 As[128 * 64];
    __shared__ __align__(16) _Float16 Bs[128 * 64];
    __shared__ float gs[8 * 128];      // gate, transposed [e][row]
    __shared__ float bs[8 * 128];      // bias slice [e][col]

    const int tid  = threadIdx.x;
    const int lane = tid & 63;
    const int wave = tid >> 6;
    const size_t n0 = (size_t)blockIdx.x * 128;
    const size_t m0 = (size_t)blockIdx.y * 128;

    {   // gate block -> transposed [e][row]
        float4 v = ((const float4*)(g + m0 * 8))[tid];
        int row = tid >> 1, e0 = (tid & 1) * 4;
        gs[(e0 + 0) * 128 + row] = v.x;
        gs[(e0 + 1) * 128 + row] = v.y;
        gs[(e0 + 2) * 128 + row] = v.z;
        gs[(e0 + 3) * 128 + row] = v.w;
    }
#pragma unroll
    for (int r = 0; r < 4; ++r) {       // bias slice
        int idx = r * 256 + tid;
        int eb = idx >> 7, col = idx & 127;
        bs[idx] = be[(size_t)eb * 1024 + n0 + col];
    }
    __syncthreads();

    // Staging: linear 16B chunk L = tid -> LDS row (within j-round) rb = tid>>3,
    // phys slot = tid&7. Source chunk kc = (tid&7) ^ f(row), f(r)=(r&7)^((r>>3)&7).
    // Row = j*32 + rb -> f = (rb&7) ^ (rb>>3) ^ 4*(j&1): even/odd-j pointer pair.
    const int rb  = tid >> 3;
    const int c8e = (tid & 7) ^ (rb & 7) ^ (rb >> 3);
    const int c8o = c8e ^ 4;
    const _Float16* pAe = xh + (m0 + rb) * (size_t)IN_F + c8e * 8;
    const _Float16* pAo = xh + (m0 + rb) * (size_t)IN_F + c8o * 8;
    const _Float16* pBe = wt + (n0 + rb) * (size_t)KT + c8e * 8;
    const _Float16* pBo = wt + (n0 + rb) * (size_t)KT + c8o * 8;
    char* lA = (char*)As + tid * 16;
    char* lB = (char*)Bs + tid * 16;

    // 32x32 fragment geometry. Wave tile 64x64 at (wm, wn); sub-tiles tm,tn in {0,1}.
    const int m32 = lane & 31;
    const int hk  = lane >> 5;           // k-half: k = hk*8 + j
    const int wm  = (wave >> 1) * 64;
    const int wn  = (wave & 1) * 64;
    // LDS byte addr: row r, k-step ks: r*128 + (((ks*2+hk) ^ f(r)) * 16)
    int raA[2][4], raB[2][4];
#pragma unroll
    for (int tm = 0; tm < 2; ++tm) {
        const int r  = wm + tm * 32 + m32;
        const int fr = (r & 7) ^ ((r >> 3) & 7);
#pragma unroll
        for (int ks = 0; ks < 4; ++ks)
            raA[tm][ks] = r * 128 + (((ks * 2 + hk) ^ fr) * 16);
    }
#pragma unroll
    for (int tn = 0; tn < 2; ++tn) {
        const int r  = wn + tn * 32 + m32;
        const int fr = (r & 7) ^ ((r >> 3) & 7);
#pragma unroll
        for (int ks = 0; ks < 4; ++ks)
            raB[tn][ks] = r * 128 + (((ks * 2 + hk) ^ fr) * 16);
    }

    // acc init = gate-weighted bias. C/D row = (reg&3) + 8*(reg>>2) + 4*hk.
    f32x16 acc[2][2] = {};
#pragma unroll
    for (int e = 0; e < 8; ++e) {
        const float bb0 = bs[e * 128 + wn + 0  + m32];
        const float bb1 = bs[e * 128 + wn + 32 + m32];
#pragma unroll
        for (int tm = 0; tm < 2; ++tm) {
#pragma unroll
            for (int r = 0; r < 16; ++r) {
                const int crow = (r & 3) + ((r >> 2) << 3) + hk * 4;
                const float gv = gs[e * 128 + wm + tm * 32 + crow];
                acc[tm][0][r] = fmaf(gv, bb0, acc[tm][0][r]);
                acc[tm][1][r] = fmaf(gv, bb1, acc[tm][1][r]);
            }
        }
    }

    // per-lane gate scalars (f16): A-fragment row = wm + tm*32 + m32 (one row/lane)
    _Float16 gh[8][2];
#pragma unroll
    for (int e = 0; e < 8; ++e)
#pragma unroll
        for (int tm = 0; tm < 2; ++tm)
            gh[e][tm] = (_Float16)gs[e * 128 + wm + tm * 32 + m32];

    // kt-outer / expert-inner, drain-immediately lockstep phases (byte-identical
    // staging/barrier structure to the proven kernel).
    for (int kt = 0; kt < 16; ++kt) {
#pragma unroll
        for (int j = 0; j < 4; ++j) {
            const _Float16* sA = ((j & 1) ? pAo : pAe) + kt * 64;
            async16(sA + j * 32 * (size_t)IN_F, lA + j * 4096);
        }

        f16x8 afr[2][4];   // raw A fragments [tm][ks] — loaded at e==0, reused across e
#pragma unroll
        for (int e = 0; e < 8; ++e) {
#pragma unroll
            for (int j = 0; j < 4; ++j) {
                const _Float16* sB = ((j & 1) ? pBo : pBe) + e * 1024 + kt * 64;
                async16(sB + j * 32 * (size_t)KT, lB + j * 4096);
            }
            __syncthreads();   // drains A (e==0) + B stagings; lockstep restoring force
            if (e == 0) {
#pragma unroll
                for (int tm = 0; tm < 2; ++tm)
#pragma unroll
                    for (int ks = 0; ks < 4; ++ks)
                        afr[tm][ks] = *(const f16x8*)((const char*)As + raA[tm][ks]);
            }
            f16x8 bf[2][4];
#pragma unroll
            for (int tn = 0; tn < 2; ++tn)
#pragma unroll
                for (int ks = 0; ks < 4; ++ks)
                    bf[tn][ks] = *(const f16x8*)((const char*)Bs + raB[tn][ks]);
            // gate-scale A fragments (per-lane scalar splat), then 16 MFMA 32x32x16
#pragma unroll
            for (int tm = 0; tm < 2; ++tm) {
                f16x8 af[4];
#pragma unroll
                for (int ks = 0; ks < 4; ++ks) af[ks] = afr[tm][ks] * gh[e][tm];
#pragma unroll
                for (int tn = 0; tn < 2; ++tn)
#pragma unroll
                    for (int ks = 0; ks < 4; ++ks)
                        acc[tm][tn] = __builtin_amdgcn_mfma_f32_32x32x16_f16(
                            af[ks], bf[tn][ks], acc[tm][tn], 0, 0, 0);
            }
            __syncthreads();   // all waves done with Bs (and As on last e) before restage
        }
    }

    // Epilogue: C/D col = lane&31, row = (reg&3) + 8*(reg>>2) + 4*hk.
#pragma unroll
    for (int tm = 0; tm < 2; ++tm) {
#pragma unroll
        for (int tn = 0; tn < 2; ++tn) {
            const size_t col = n0 + wn + tn * 32 + m32;
#pragma unroll
            for (int r = 0; r < 16; ++r) {
                const int crow = (r & 3) + ((r >> 2) << 3) + hk * 4;
                out[(m0 + wm + tm * 32 + crow) * (size_t)OUT_F + col] = acc[tm][tn][r];
            }
        }
    }
}

extern "C" void kernel_launch(void* const* d_in, const int* in_sizes, int n_in,
                              void* d_out, int out_size, void* d_ws, size_t ws_size,
                              hipStream_t stream) {
    const float* x  = (const float*)d_in[0];
    const float* We = (const float*)d_in[1];
    const float* be = (const float*)d_in[2];
    const float* Wg = (const float*)d_in[3];
    const float* bg = (const float*)d_in[4];
    float* out = (float*)d_out;

    char* ws = (char*)d_ws;
    float*    g   = (float*)ws;                                  // 256 KB
    _Float16* xh  = (_Float16*)(ws + (1 << 18));                 // 16 MiB
    _Float16* wt2 = (_Float16*)(ws + (1 << 18) + (1 << 24));     // 16 MiB

    moe_prep_kernel<<<2560, 256, 0, stream>>>(x, Wg, bg, We, g, xh, wt2);
    moe_gemm_kernel<<<dim3(OUT_F / 128, M_TOK / 128), 256, 0, stream>>>(xh, wt2, g, be, out);
}

// Round 14
// 239.503 us; speedup vs baseline: 1.0342x; 1.0228x over previous
//
#include <hip/hip_runtime.h>
#include <hip/hip_bf16.h>

#define M_TOK 8192
#define IN_F  1024
#define OUT_F 1024
#define N_EXP 8
#define KT    8192   // stacked K: 8 experts x 1024 (B side only)

typedef __attribute__((ext_vector_type(8))) _Float16 f16x8;
typedef __attribute__((ext_vector_type(4))) _Float16 f16x4;
typedef __attribute__((ext_vector_type(4))) float    f32x4;

// ---------------- merged prep: gate+convert (blocks 0..511) | transpose (512..2559) ----------------
// Proven round-9/11: transpose blocks backfill CUs the 512-block gate leaves idle.
__global__ __launch_bounds__(256) void moe_prep_kernel(
    const float* __restrict__ x, const float* __restrict__ Wg,
    const float* __restrict__ bg, const float* __restrict__ We,
    float* __restrict__ g, _Float16* __restrict__ xh, _Float16* __restrict__ wt)
{
    __shared__ float t[64][65];
    const int bid = blockIdx.x;
    if (bid < 512) {
        // ---- gate softmax + x -> f16, 16 tokens/block (4 per wave) ----
        const int lane = threadIdx.x & 63;
        const int wave = threadIdx.x >> 6;
        const int t0 = bid * 16 + wave * 4;
        const float* xr0 = x + (size_t)t0 * IN_F;

        float acc[4][8] = {};
#pragma unroll
        for (int kc = 0; kc < 4; ++kc) {
            const int i = kc * 256 + lane * 4;
            float4 xv[4];
#pragma unroll
            for (int tk = 0; tk < 4; ++tk) xv[tk] = *(const float4*)(xr0 + (size_t)tk * IN_F + i);
            float xs[4][4];
#pragma unroll
            for (int tk = 0; tk < 4; ++tk) {
                xs[tk][0] = xv[tk].x; xs[tk][1] = xv[tk].y;
                xs[tk][2] = xv[tk].z; xs[tk][3] = xv[tk].w;
            }
#pragma unroll
            for (int j = 0; j < 4; ++j) {
                const float4* wr = (const float4*)(Wg + (size_t)(i + j) * 8);
                float4 w0 = wr[0], w1 = wr[1];
                float wv[8] = {w0.x, w0.y, w0.z, w0.w, w1.x, w1.y, w1.z, w1.w};
#pragma unroll
                for (int tk = 0; tk < 4; ++tk)
#pragma unroll
                    for (int e = 0; e < 8; ++e)
                        acc[tk][e] = fmaf(xs[tk][j], wv[e], acc[tk][e]);
            }
#pragma unroll
            for (int tk = 0; tk < 4; ++tk) {
                f16x4 h = { (_Float16)xs[tk][0], (_Float16)xs[tk][1],
                            (_Float16)xs[tk][2], (_Float16)xs[tk][3] };
                *(f16x4*)(xh + (size_t)(t0 + tk) * IN_F + i) = h;
            }
        }
#pragma unroll
        for (int tk = 0; tk < 4; ++tk) {
            float a[8];
#pragma unroll
            for (int e = 0; e < 8; ++e) {
                float v = acc[tk][e];
#pragma unroll
                for (int off = 32; off > 0; off >>= 1) v += __shfl_xor(v, off, 64);
                a[e] = v + bg[e];
            }
            float mx = a[0];
#pragma unroll
            for (int e = 1; e < 8; ++e) mx = fmaxf(mx, a[e]);
            float sum = 0.f;
#pragma unroll
            for (int e = 0; e < 8; ++e) { a[e] = __expf(a[e] - mx); sum += a[e]; }
            float inv = 1.0f / sum;
            if (lane == 0) {
                float4 p0 = {a[0] * inv, a[1] * inv, a[2] * inv, a[3] * inv};
                float4 p1 = {a[4] * inv, a[5] * inv, a[6] * inv, a[7] * inv};
                float4* gp = (float4*)(g + (size_t)(t0 + tk) * 8);
                gp[0] = p0; gp[1] = p1;
            }
        }
    } else {
        // ---- We [e][i][o] fp32 -> wt [o][e*1024+i] f16, one 64x64 tile ----
        const int tile = bid - 512;
        const int e  = tile >> 8;
        const int o0 = ((tile >> 4) & 15) * 64;
        const int i0 = (tile & 15) * 64;
        const float* src = We + ((size_t)e << 20);
        const int oo = threadIdx.x & 63;
        const int ib = threadIdx.x >> 6;
#pragma unroll
        for (int r = 0; r < 16; ++r) {
            int i = ib + r * 4;
            t[i][oo] = src[(size_t)(i0 + i) * OUT_F + o0 + oo];
        }
        __syncthreads();
        const int i8 = threadIdx.x & 7;      // i-block (8 consecutive i)
        const int ob = threadIdx.x >> 3;     // 0..31
#pragma unroll
        for (int h = 0; h < 2; ++h) {
            const int o = ob + h * 32;
            float v[8];
#pragma unroll
            for (int j = 0; j < 8; ++j) v[j] = t[i8 * 8 + j][o];
            f16x8 hv = { (_Float16)v[0], (_Float16)v[1], (_Float16)v[2], (_Float16)v[3],
                         (_Float16)v[4], (_Float16)v[5], (_Float16)v[6], (_Float16)v[7] };
            *(f16x8*)(wt + (size_t)(o0 + o) * KT + (size_t)e * 1024 + i0 + i8 * 8) = hv;
        }
    }
}

// ---------------- fused GEMM: out = sum_e g[:,e]*(xh@We[e]) + g-weighted bias ----
// FINAL: round-5/11 proven schedule, byte-identical (137.3us / FETCH 76.7MB /
// Mfma 45% / conflicts 16K). Nine measured deviations all regressed:
// counted-vmcnt 218us, 2-expert-phase 162, dbuf-pipeline 222, 512-thr 161,
// device-barrier fusion 358, NT hints 148, expert-rotation 161, 32x32 naive 143,
// 32x32 swizzle-fixed 140. Mechanism (counter-validated): drain-immediately
// phases keep the same-XCD cohort time-aligned; co-resident blocks (same n0)
// stage the SAME B slice in-phase (2nd copy = L2 hit); laggards self-correct
// because L2-hit drains are shorter. Latency-hiding breaks the alignment ->
// B re-fetch from HBM (FETCH 410MB) and slower drains. The ~1330cyc/phase drain
// is the price of the equilibrium; the MFMA-shape lever (32x32, -200cyc compute)
// verified that the phase is drain-floor-limited, not issue-limited.
__device__ __forceinline__ void async16(const void* gp, void* lp) {
    __builtin_amdgcn_global_load_lds((const __attribute__((address_space(1))) void*)gp,
                                     (__attribute__((address_space(3))) void*)lp, 16, 0, 0);
}

__global__ __launch_bounds__(256, 2) void moe_gemm_kernel(
    const _Float16* __restrict__ xh,   // [M][1024] f16
    const _Float16* __restrict__ wt,   // [N][KT] f16  (stacked B'^T)
    const float* __restrict__ g,       // [M][E]
    const float* __restrict__ be,      // [E][N]
    float* __restrict__ out)           // [M][N] fp32
{
    __shared__ __align__(16) _Float16 As[128 * 64];
    __shared__ __align__(16) _Float16 Bs[128 * 64];
    __shared__ float gs[8 * 128];      // gate, transposed [e][row]
    __shared__ float bs[8 * 128];      // bias slice [e][col]

    const int tid  = threadIdx.x;
    const int lane = tid & 63;
    const int wave = tid >> 6;
    const size_t n0 = (size_t)blockIdx.x * 128;
    const size_t m0 = (size_t)blockIdx.y * 128;

    {   // gate block -> transposed [e][row]
        float4 v = ((const float4*)(g + m0 * 8))[tid];
        int row = tid >> 1, e0 = (tid & 1) * 4;
        gs[(e0 + 0) * 128 + row] = v.x;
        gs[(e0 + 1) * 128 + row] = v.y;
        gs[(e0 + 2) * 128 + row] = v.z;
        gs[(e0 + 3) * 128 + row] = v.w;
    }
#pragma unroll
    for (int r = 0; r < 4; ++r) {       // bias slice
        int idx = r * 256 + tid;
        int eb = idx >> 7, col = idx & 127;
        bs[idx] = be[(size_t)eb * 1024 + n0 + col];
    }
    __syncthreads();

    // Staging: linear 16B chunk L = tid -> LDS row = L>>3, phys c8 = L&7.
    // XOR swizzle baked into the GLOBAL source: logical k-chunk = phys_c8 ^ (row&7).
    const int rb = tid >> 3;
    const int c8 = (tid & 7) ^ (rb & 7);
    const _Float16* pA = xh + (m0 + rb) * (size_t)IN_F + c8 * 8;
    const _Float16* pB = wt + (n0 + rb) * (size_t)KT + c8 * 8;
    char* lA = (char*)As + tid * 16;
    char* lB = (char*)Bs + tid * 16;

    // Fragment read addresses (bytes). A[m=lane&15][k=quad*8+j]; phys c8 = c8_logical ^ (row&7)
    const int quad = lane >> 4;
    const int ml   = lane & 15;
    const int wm   = (wave >> 1) * 64;
    const int wn   = (wave & 1) * 64;
    const int raA0 = (wm + ml) * 128 + (((0 * 4 + quad) ^ (lane & 7)) * 16);
    const int raA1 = (wm + ml) * 128 + (((1 * 4 + quad) ^ (lane & 7)) * 16);
    const int raB0 = (wn + ml) * 128 + (((0 * 4 + quad) ^ (lane & 7)) * 16);
    const int raB1 = (wn + ml) * 128 + (((1 * 4 + quad) ^ (lane & 7)) * 16);

    // acc init = gate-weighted bias: acc[i][jn][r] = sum_e g[row,e]*be[e,col]
    f32x4 acc[4][4] = {};
#pragma unroll
    for (int e = 0; e < 8; ++e) {
        float ge[4][4], bb[4];
#pragma unroll
        for (int i = 0; i < 4; ++i)
#pragma unroll
            for (int r = 0; r < 4; ++r) ge[i][r] = gs[e * 128 + wm + i * 16 + quad * 4 + r];
#pragma unroll
        for (int jn = 0; jn < 4; ++jn) bb[jn] = bs[e * 128 + wn + jn * 16 + ml];
#pragma unroll
        for (int i = 0; i < 4; ++i)
#pragma unroll
            for (int jn = 0; jn < 4; ++jn)
#pragma unroll
                for (int r = 0; r < 4; ++r)
                    acc[i][jn][r] = fmaf(ge[i][r], bb[jn], acc[i][jn][r]);
    }

    // per-lane gate scalars (f16) for the 4 m-tiles x 8 experts this lane touches
    _Float16 gh[8][4];
#pragma unroll
    for (int e = 0; e < 8; ++e)
#pragma unroll
        for (int t = 0; t < 4; ++t)
            gh[e][t] = (_Float16)gs[e * 128 + wm + t * 16 + ml];

    // kt-outer / expert-inner: A-tile staged ONCE per kt (4 async16); B per expert.
    // af fragments are expert-invariant -> load once per kt, scale per expert.
    for (int kt = 0; kt < 16; ++kt) {
        const _Float16* sA = pA + kt * 64;
#pragma unroll
        for (int j = 0; j < 4; ++j) async16(sA + j * 32 * (size_t)IN_F, lA + j * 4096);

        f16x8 afr[2][4];   // raw A fragments for s=0,1 — loaded at e==0, reused across e
#pragma unroll
        for (int e = 0; e < 8; ++e) {
            const _Float16* sB = pB + e * 1024 + kt * 64;
#pragma unroll
            for (int j = 0; j < 4; ++j) async16(sB + j * 32 * (size_t)KT, lB + j * 4096);
            __syncthreads();   // drains A (e==0) + B stagings; lockstep restoring force
            if (e == 0) {
#pragma unroll
                for (int t = 0; t < 4; ++t) {
                    afr[0][t] = *(const f16x8*)((const char*)As + raA0 + t * 2048);
                    afr[1][t] = *(const f16x8*)((const char*)As + raA1 + t * 2048);
                }
            }
#pragma unroll
            for (int s = 0; s < 2; ++s) {
                const int rB = s ? raB1 : raB0;
                f16x8 af[4], bf[4];
#pragma unroll
                for (int t = 0; t < 4; ++t) bf[t] = *(const f16x8*)((const char*)Bs + rB + t * 2048);
                // gate-scale A fragments: per-lane scalar splat (v_pk_mul_f16)
#pragma unroll
                for (int t = 0; t < 4; ++t) af[t] = afr[s][t] * gh[e][t];
#pragma unroll
                for (int i = 0; i < 4; ++i)
#pragma unroll
                    for (int jn = 0; jn < 4; ++jn)
                        acc[i][jn] = __builtin_amdgcn_mfma_f32_16x16x32_f16(af[i], bf[jn], acc[i][jn], 0, 0, 0);
            }
            __syncthreads();   // all waves done with Bs (and As on last e) before restage
        }
    }

    // Epilogue: plain coalesced stores. C/D layout col = lane&15, row = quad*4 + reg.
#pragma unroll
    for (int i = 0; i < 4; ++i) {
        const int rowb = wm + i * 16 + quad * 4;
#pragma unroll
        for (int jn = 0; jn < 4; ++jn) {
            const size_t col = n0 + wn + jn * 16 + ml;
#pragma unroll
            for (int r = 0; r < 4; ++r)
                out[(m0 + rowb + r) * (size_t)OUT_F + col] = acc[i][jn][r];
        }
    }
}

extern "C" void kernel_launch(void* const* d_in, const int* in_sizes, int n_in,
                              void* d_out, int out_size, void* d_ws, size_t ws_size,
                              hipStream_t stream) {
    const float* x  = (const float*)d_in[0];
    const float* We = (const float*)d_in[1];
    const float* be = (const float*)d_in[2];
    const float* Wg = (const float*)d_in[3];
    const float* bg = (const float*)d_in[4];
    float* out = (float*)d_out;

    char* ws = (char*)d_ws;
    float*    g   = (float*)ws;                                  // 256 KB
    _Float16* xh  = (_Float16*)(ws + (1 << 18));                 // 16 MiB
    _Float16* wt2 = (_Float16*)(ws + (1 << 18) + (1 << 24));     // 16 MiB

    moe_prep_kernel<<<2560, 256, 0, stream>>>(x, Wg, bg, We, g, xh, wt2);
    moe_gemm_kernel<<<dim3(OUT_F / 128, M_TOK / 128), 256, 0, stream>>>(xh, wt2, g, be, out);
}